// Round 8
// baseline (546.393 us; speedup 1.0000x reference)
//
#include <hip/hip_runtime.h>

// Problem constants (fixed by setup_inputs)
#define BQ   16
#define HH   512
#define WW   512
#define CC   3
#define PSZ  16
#define STR  8
#define PYN  63
#define PXN  63
#define NPATCH (BQ * PYN * PXN)   // 63504
#define HID  512
#define MT   48                   // patches per block; 63504/48 = 1323 exactly
#define NTH  512                  // 8 waves, each owns a 64-col N slice, all 3 M-tiles
#define KSTEPS 48                 // 1536 / 32

typedef __attribute__((ext_vector_type(8))) short  short8;
typedef __attribute__((ext_vector_type(4))) float  f32x4;

__device__ __forceinline__ ushort f2bf(float f) {
    unsigned u = __float_as_uint(f);
    u = (u + 0x7fffu + ((u >> 16) & 1u)) >> 16;   // RNE
    return (ushort)u;
}
__device__ __forceinline__ float bf2f(ushort h) {
    return __uint_as_float(((unsigned)h) << 16);
}
__device__ __forceinline__ unsigned pk2(float a, float b) {
    return (unsigned)f2bf(a) | ((unsigned)f2bf(b) << 16);
}

// Pack w1[0:1536][0:512] -> bf16, lane-linear fragment order:
// idx = ((s*32 + ntg)*64 + g*16 + cn)*8 + kk,  s=k>>5, g=(k>>3)&3, kk=k&7, ntg=n>>4, cn=n&15.
// => per (s,ntg) the 64 lane-fragments are 1024B contiguous (conflict-free / coalesced).
__global__ void pack_w1_kernel(const float* __restrict__ w1, ushort* __restrict__ w1p) {
    int e = blockIdx.x * 256 + threadIdx.x;   // 0 .. 1536*512-1
    int k = e >> 9;
    int n = e & 511;
    int idx = ((k >> 5) << 14) + ((n >> 4) << 9) + (((k >> 3) & 3) << 7) + ((n & 15) << 3) + (k & 7);
    w1p[idx] = f2bf(w1[e]);
}

__global__ __launch_bounds__(NTH)
void lfe_mfma_kernel(const float* __restrict__ img1,
                     const float* __restrict__ img2,
                     const float* __restrict__ prior,
                     const float* __restrict__ w1,
                     const float* __restrict__ b1,
                     const float* __restrict__ w2,
                     const float* __restrict__ b2,
                     const ushort* __restrict__ w1p,
                     float* __restrict__ out)
{
    // feat: A-fragment order. Element (patch pi, k) lives at
    //   ((m*48 + s)*64 + g*16 + cn)*8 + kk,  m=pi>>4, cn=pi&15, s=k>>5, g=(k>>3)&3, kk=k&7
    // = (pi>>4)*24576 + (k>>3)*128 + (pi&15)*8 + (k&7)
    __shared__ ushort feat[3 * KSTEPS * 512];   // 147456 B
    __shared__ float  red[8][MT][2];            // 3072 B
    __shared__ float  srem[MT][2];
    __shared__ float  sflow[MT][2];
    __shared__ int    sip[MT][2];
    __shared__ int    sbase1[MT];
    __shared__ int    sbase2[MT];

    const int t    = threadIdx.x;
    const int wid  = t >> 6;
    const int lane = t & 63;
    const int n0   = blockIdx.x * MT;

    // ---- Phase 0: prior -> int/remainder + patch base offsets ----
    if (t < MT) {
        int n = n0 + t;
        float py_ = prior[(size_t)n * 2 + 0];
        float px_ = prior[(size_t)n * 2 + 1];
        int ipy = (int)rintf(py_);   // RNE == jnp.round
        int ipx = (int)rintf(px_);
        sip[t][0] = ipy; sip[t][1] = ipx;
        srem[t][0] = py_ - (float)ipy;
        srem[t][1] = px_ - (float)ipx;
        int b  = n / (PYN * PXN);
        int r  = n % (PYN * PXN);
        int py = r / PXN, px = r % PXN;
        int by = py * STR, bx = px * STR;
        int sy = min(max(by + ipy, 0), HH - PSZ);
        int sx = min(max(bx + ipx, 0), WW - PSZ);
        sbase1[t] = ((b * HH + by) * WW + bx) * CC;
        sbase2[t] = ((b * HH + sy) * WW + sx) * CC;
    }
    __syncthreads();

    // ---- Phase 1: stage patches (bf16) directly in fragment order ----
    // 576 combos (m, s, g); wave handles 72; lane covers (patch m*16 + lane>>2, kk2 = lane&3).
    // LDS write banks: (g*64 + (lane>>2)*4 + (lane&3)) dwords -> all 32 banks 2-way (free).
    {
        const int plo = lane >> 2;
        const int kk2 = lane & 3;
        #pragma unroll 4
        for (int i = 0; i < 72; ++i) {
            int c = (i << 3) + wid;          // 0..575
            int m = c / 192;
            int r = c - m * 192;
            int s = r >> 2, g = r & 3;
            int pi = (m << 4) + plo;
            int ka = (s << 5) + (g << 3) + (kk2 << 1);   // absolute k (even)
            const float* src;
            int e;
            if (ka < 768) { src = img1 + sbase1[pi]; e = ka; }
            else          { src = img2 + sbase2[pi]; e = ka - 768; }
            int yi  = e / 48;                 // uniform per instr (proved: no 48-boundary cross)
            int off = e - yi * 48;
            const float* g8 = src + yi * (WW * CC) + off;
            float va = g8[0], vb = g8[1];
            int idx = ((m * KSTEPS + s) << 9) + (g << 7) + (plo << 3) + (kk2 << 1);
            *(unsigned*)(&feat[idx]) = pk2(va, vb);
        }
    }
    __syncthreads();

    // ---- Phase 2: MFMA GEMM, B in registers (double-buffered), NO barriers ----
    const int cn = lane & 15;
    const int g  = lane >> 4;

    f32x4 acc[3][4];
    #pragma unroll
    for (int m = 0; m < 3; ++m)
        #pragma unroll
        for (int nt = 0; nt < 4; ++nt) acc[m][nt] = f32x4{0.f, 0.f, 0.f, 0.f};

    const int ntb = wid << 2;                         // first ntg of this wave's slice
    const ushort* bbase = w1p + ((size_t)lane << 3);
    const ushort* fb = feat + lane * 8;

    short8 B0[4], B1[4];
    #define LOADB(B, s_) {                                            \
        const ushort* p_ = bbase + ((size_t)(((s_) << 5) + ntb) << 9);\
        B[0] = *(const short8*)(p_);                                  \
        B[1] = *(const short8*)(p_ + 512);                            \
        B[2] = *(const short8*)(p_ + 1024);                           \
        B[3] = *(const short8*)(p_ + 1536);                           \
    }
    LOADB(B0, 0);

    for (int s = 0; s < KSTEPS; s += 2) {
        LOADB(B1, s + 1);
        {
            short8 A0 = *(const short8*)(fb + ((0 * KSTEPS + s) << 9));
            short8 A1 = *(const short8*)(fb + ((1 * KSTEPS + s) << 9));
            short8 A2 = *(const short8*)(fb + ((2 * KSTEPS + s) << 9));
            #pragma unroll
            for (int nt = 0; nt < 4; ++nt) {
                acc[0][nt] = __builtin_amdgcn_mfma_f32_16x16x32_bf16(A0, B0[nt], acc[0][nt], 0, 0, 0);
                acc[1][nt] = __builtin_amdgcn_mfma_f32_16x16x32_bf16(A1, B0[nt], acc[1][nt], 0, 0, 0);
                acc[2][nt] = __builtin_amdgcn_mfma_f32_16x16x32_bf16(A2, B0[nt], acc[2][nt], 0, 0, 0);
            }
        }
        int s2 = (s + 2 < KSTEPS) ? s + 2 : KSTEPS - 1;   // clamped dummy at tail
        LOADB(B0, s2);
        {
            short8 A0 = *(const short8*)(fb + ((0 * KSTEPS + s + 1) << 9));
            short8 A1 = *(const short8*)(fb + ((1 * KSTEPS + s + 1) << 9));
            short8 A2 = *(const short8*)(fb + ((2 * KSTEPS + s + 1) << 9));
            #pragma unroll
            for (int nt = 0; nt < 4; ++nt) {
                acc[0][nt] = __builtin_amdgcn_mfma_f32_16x16x32_bf16(A0, B1[nt], acc[0][nt], 0, 0, 0);
                acc[1][nt] = __builtin_amdgcn_mfma_f32_16x16x32_bf16(A1, B1[nt], acc[1][nt], 0, 0, 0);
                acc[2][nt] = __builtin_amdgcn_mfma_f32_16x16x32_bf16(A2, B1[nt], acc[2][nt], 0, 0, 0);
            }
        }
    }
    #undef LOADB

    // ---- Phase 3: epilogue — rem features + b1, ReLU, fold w2, reduce over cn ----
    float ps[3][4][2];
    #pragma unroll
    for (int m = 0; m < 3; ++m)
        #pragma unroll
        for (int r = 0; r < 4; ++r) { ps[m][r][0] = 0.f; ps[m][r][1] = 0.f; }

    #pragma unroll
    for (int nt = 0; nt < 4; ++nt) {
        int j = (wid << 6) + (nt << 4) + cn;
        float w1a = w1[(size_t)1536 * HID + j];
        float w1b = w1[(size_t)1537 * HID + j];
        float bb  = b1[j];
        float w20 = w2[(size_t)j * 2 + 0];
        float w21 = w2[(size_t)j * 2 + 1];
        #pragma unroll
        for (int m = 0; m < 3; ++m) {
            #pragma unroll
            for (int r = 0; r < 4; ++r) {
                int pr = (m << 4) + (g << 2) + r;   // C/D: row = (lane>>4)*4 + reg
                float h = acc[m][nt][r] + bb + srem[pr][0] * w1a + srem[pr][1] * w1b;
                h = fmaxf(h, 0.f);
                ps[m][r][0] = fmaf(h, w20, ps[m][r][0]);
                ps[m][r][1] = fmaf(h, w21, ps[m][r][1]);
            }
        }
    }
    #pragma unroll
    for (int m = 0; m < 3; ++m)
        #pragma unroll
        for (int r = 0; r < 4; ++r)
            #pragma unroll
            for (int cc = 0; cc < 2; ++cc)
                #pragma unroll
                for (int off = 1; off < 16; off <<= 1)
                    ps[m][r][cc] += __shfl_xor(ps[m][r][cc], off, 64);
    if (cn == 0) {
        #pragma unroll
        for (int m = 0; m < 3; ++m)
            #pragma unroll
            for (int r = 0; r < 4; ++r) {
                int pr = (m << 4) + (g << 2) + r;
                red[wid][pr][0] = ps[m][r][0];
                red[wid][pr][1] = ps[m][r][1];
            }
    }
    __syncthreads();
    if (t < MT * 2) {
        int pr = t >> 1, c = t & 1;
        float v = b2[c];
        #pragma unroll
        for (int w = 0; w < 8; ++w) v += red[w][pr][c];
        sflow[pr][c] = srem[pr][c] + v;   // remainder_flow
    }
    __syncthreads();

    // ---- Phase 4: bilinear warp loss, 8 lanes per patch (xj = lt, lt+8) ----
    {
        const int gi = t >> 3, lt = t & 7;
        if (gi < MT) {
            const int pi = gi;
            const float rfy = sflow[pi][0], rfx = sflow[pi][1];
            const int pbase = (pi >> 4) * 24576 + ((pi & 15) << 3);
            float lsum = 0.f;
            #pragma unroll
            for (int xh = 0; xh < 2; ++xh) {
                int xj = lt + (xh << 3);
                float x  = (float)xj + rfx;
                int   x0 = min(max((int)floorf(x), 0), PSZ - 1);
                int   x1 = min(x0 + 1, PSZ - 1);
                float wx = fminf(fmaxf(x - (float)x0, 0.f), 1.f);
                int   c0 = x0 * 3, c1 = x1 * 3;
                #pragma unroll 4
                for (int yi = 0; yi < PSZ; ++yi) {
                    float y  = (float)yi + rfy;
                    int   y0 = min(max((int)floorf(y), 0), PSZ - 1);
                    int   y1 = min(y0 + 1, PSZ - 1);
                    float wy = fminf(fmaxf(y - (float)y0, 0.f), 1.f);
                    int r0 = 768 + y0 * 48, r1 = 768 + y1 * 48;
                    int ep = yi * 48 + xj * 3;
                    #pragma unroll
                    for (int cc = 0; cc < 3; ++cc) {
                        int k00 = r0 + c0 + cc, k01 = r0 + c1 + cc;
                        int k10 = r1 + c0 + cc, k11 = r1 + c1 + cc;
                        float v00 = bf2f(feat[pbase + ((k00 >> 3) << 7) + (k00 & 7)]);
                        float v01 = bf2f(feat[pbase + ((k01 >> 3) << 7) + (k01 & 7)]);
                        float v10 = bf2f(feat[pbase + ((k10 >> 3) << 7) + (k10 & 7)]);
                        float v11 = bf2f(feat[pbase + ((k11 >> 3) << 7) + (k11 & 7)]);
                        float a = v00 + wx * (v01 - v00);
                        float b = v10 + wx * (v11 - v10);
                        float warped = a + wy * (b - a);
                        int kp = ep + cc;
                        float d = warped - bf2f(feat[pbase + ((kp >> 3) << 7) + (kp & 7)]);
                        lsum = fmaf(d, d, lsum);
                    }
                }
            }
            #pragma unroll
            for (int off = 1; off < 8; off <<= 1)
                lsum += __shfl_xor(lsum, off, 64);

            if (lt == 0) {
                int n = n0 + pi;
                out[(size_t)n * 3 + 0] = (float)sip[pi][0] + rfy;
                out[(size_t)n * 3 + 1] = (float)sip[pi][1] + rfx;
                out[(size_t)n * 3 + 2] = lsum * (1.f / 768.f);
            }
        }
    }
}

extern "C" void kernel_launch(void* const* d_in, const int* in_sizes, int n_in,
                              void* d_out, int out_size, void* d_ws, size_t ws_size,
                              hipStream_t stream) {
    const float* img1  = (const float*)d_in[0];
    const float* img2  = (const float*)d_in[1];
    const float* prior = (const float*)d_in[2];
    const float* w1    = (const float*)d_in[3];
    const float* b1    = (const float*)d_in[4];
    const float* w2    = (const float*)d_in[5];
    const float* b2    = (const float*)d_in[6];
    float* out = (float*)d_out;
    ushort* w1p = (ushort*)d_ws;            // 1536*512*2 B = 1.57 MB

    pack_w1_kernel<<<dim3((1536 * HID) / 256), dim3(256), 0, stream>>>(w1, w1p);

    dim3 grid(NPATCH / MT);                 // 1323 blocks, exact
    dim3 block(NTH);
    lfe_mfma_kernel<<<grid, block, 0, stream>>>(img1, img2, prior, w1, b1, w2, b2, w1p, out);
}

// Round 9
// 403.462 us; speedup vs baseline: 1.3543x; 1.3543x over previous
//
#include <hip/hip_runtime.h>

// Problem constants (fixed by setup_inputs)
#define BQ   16
#define HH   512
#define WW   512
#define CC   3
#define PSZ  16
#define STR  8
#define PYN  63
#define PXN  63
#define NPATCH (BQ * PYN * PXN)   // 63504
#define HID  512
#define MT   48                   // patches per block; 63504/48 = 1323 exactly
#define NTH  1024                 // 16 waves: each owns a 32-col N slice, all 3 M-tiles
#define KSTEPS 48                 // 1536 / 32

typedef __attribute__((ext_vector_type(8))) short  short8;
typedef __attribute__((ext_vector_type(4))) float  f32x4;

__device__ __forceinline__ ushort f2bf(float f) {
    unsigned u = __float_as_uint(f);
    u = (u + 0x7fffu + ((u >> 16) & 1u)) >> 16;   // RNE
    return (ushort)u;
}
__device__ __forceinline__ float bf2f(ushort h) {
    return __uint_as_float(((unsigned)h) << 16);
}
__device__ __forceinline__ unsigned pk2(float a, float b) {
    return (unsigned)f2bf(a) | ((unsigned)f2bf(b) << 16);
}

// Pack w1[0:1536][0:512] -> bf16, lane-linear fragment order:
// idx = ((s*32 + ntg)*64 + g*16 + cn)*8 + kk,  s=k>>5, g=(k>>3)&3, kk=k&7, ntg=n>>4, cn=n&15.
// => per (s,ntg) the 64 lane-fragments are 1024B contiguous (conflict-free / coalesced).
__global__ void pack_w1_kernel(const float* __restrict__ w1, ushort* __restrict__ w1p) {
    int e = blockIdx.x * 256 + threadIdx.x;   // 0 .. 1536*512-1
    int k = e >> 9;
    int n = e & 511;
    int idx = ((k >> 5) << 14) + ((n >> 4) << 9) + (((k >> 3) & 3) << 7) + ((n & 15) << 3) + (k & 7);
    w1p[idx] = f2bf(w1[e]);
}

__global__ __launch_bounds__(NTH)
void lfe_mfma_kernel(const float* __restrict__ img1,
                     const float* __restrict__ img2,
                     const float* __restrict__ prior,
                     const float* __restrict__ w1,
                     const float* __restrict__ b1,
                     const float* __restrict__ w2,
                     const float* __restrict__ b2,
                     const ushort* __restrict__ w1p,
                     float* __restrict__ out)
{
    // feat: A-fragment order. Element (patch pi, k) lives at
    //   (pi>>4)*24576 + (k>>3)*128 + (pi&15)*8 + (k&7)
    __shared__ ushort feat[3 * KSTEPS * 512];   // 147456 B
    __shared__ float  red[16][MT][2];           // 6144 B
    __shared__ float  srem[MT][2];
    __shared__ float  sflow[MT][2];
    __shared__ int    sip[MT][2];
    __shared__ int    sbase1[MT];
    __shared__ int    sbase2[MT];

    const int t    = threadIdx.x;
    const int wid  = t >> 6;         // 0..15
    const int lane = t & 63;
    const int n0   = blockIdx.x * MT;

    // ---- Hoisted B prefetch (independent of feat; hides under staging) ----
    const int ntb = wid << 1;                      // first ntg of this wave's 32-col slice
    const ushort* bbase = w1p + ((size_t)lane << 3);
    short8 B0[2], B1[2];
    #define LOADB(B, s_) {                                            \
        const ushort* p_ = bbase + ((size_t)(((s_) << 5) + ntb) << 9);\
        B[0] = *(const short8*)(p_);                                  \
        B[1] = *(const short8*)(p_ + 512);                            \
    }
    LOADB(B0, 0);
    LOADB(B1, 1);

    // ---- Phase 0: prior -> int/remainder + patch base offsets ----
    if (t < MT) {
        int n = n0 + t;
        float py_ = prior[(size_t)n * 2 + 0];
        float px_ = prior[(size_t)n * 2 + 1];
        int ipy = (int)rintf(py_);   // RNE == jnp.round
        int ipx = (int)rintf(px_);
        sip[t][0] = ipy; sip[t][1] = ipx;
        srem[t][0] = py_ - (float)ipy;
        srem[t][1] = px_ - (float)ipx;
        int b  = n / (PYN * PXN);
        int r  = n % (PYN * PXN);
        int py = r / PXN, px = r % PXN;
        int by = py * STR, bx = px * STR;
        int sy = min(max(by + ipy, 0), HH - PSZ);
        int sx = min(max(bx + ipx, 0), WW - PSZ);
        sbase1[t] = ((b * HH + by) * WW + bx) * CC;
        sbase2[t] = ((b * HH + sy) * WW + sx) * CC;
    }
    __syncthreads();

    // ---- Phase 1: stage patches (bf16) directly in fragment order ----
    // 576 combos (m, s, g) / 16 waves = 36 per wave; lane covers (patch m*16+lane>>2, kk2=lane&3).
    {
        const int plo = lane >> 2;
        const int kk2 = lane & 3;
        #pragma unroll 4
        for (int i = 0; i < 36; ++i) {
            int c = (i << 4) + wid;          // 0..575
            int m = c / 192;
            int r = c - m * 192;
            int s = r >> 2, g = r & 3;
            int pi = (m << 4) + plo;
            int ka = (s << 5) + (g << 3) + (kk2 << 1);   // absolute k (even)
            const float* src;
            int e;
            if (ka < 768) { src = img1 + sbase1[pi]; e = ka; }
            else          { src = img2 + sbase2[pi]; e = ka - 768; }
            int yi  = e / 48;                 // uniform per instr (no 48-boundary cross)
            int off = e - yi * 48;
            const float* g8 = src + yi * (WW * CC) + off;
            float va = g8[0], vb = g8[1];
            int idx = ((m * KSTEPS + s) << 9) + (g << 7) + (plo << 3) + (kk2 << 1);
            *(unsigned*)(&feat[idx]) = pk2(va, vb);
        }
    }
    __syncthreads();

    // ---- Phase 2: MFMA GEMM, B in registers, prefetch distance 2, NO barriers ----
    const int cn = lane & 15;
    const int g  = lane >> 4;

    f32x4 acc[3][2];
    #pragma unroll
    for (int m = 0; m < 3; ++m)
        #pragma unroll
        for (int nt = 0; nt < 2; ++nt) acc[m][nt] = f32x4{0.f, 0.f, 0.f, 0.f};

    const ushort* fb = feat + lane * 8;

    for (int s = 0; s < KSTEPS; s += 2) {
        {
            short8 A0 = *(const short8*)(fb + ((0 * KSTEPS + s) << 9));
            short8 A1 = *(const short8*)(fb + ((1 * KSTEPS + s) << 9));
            short8 A2 = *(const short8*)(fb + ((2 * KSTEPS + s) << 9));
            #pragma unroll
            for (int nt = 0; nt < 2; ++nt) {
                acc[0][nt] = __builtin_amdgcn_mfma_f32_16x16x32_bf16(A0, B0[nt], acc[0][nt], 0, 0, 0);
                acc[1][nt] = __builtin_amdgcn_mfma_f32_16x16x32_bf16(A1, B0[nt], acc[1][nt], 0, 0, 0);
                acc[2][nt] = __builtin_amdgcn_mfma_f32_16x16x32_bf16(A2, B0[nt], acc[2][nt], 0, 0, 0);
            }
        }
        int sa = (s + 2 < KSTEPS) ? s + 2 : KSTEPS - 1;   // clamped dummy at tail
        LOADB(B0, sa);
        {
            short8 A0 = *(const short8*)(fb + ((0 * KSTEPS + s + 1) << 9));
            short8 A1 = *(const short8*)(fb + ((1 * KSTEPS + s + 1) << 9));
            short8 A2 = *(const short8*)(fb + ((2 * KSTEPS + s + 1) << 9));
            #pragma unroll
            for (int nt = 0; nt < 2; ++nt) {
                acc[0][nt] = __builtin_amdgcn_mfma_f32_16x16x32_bf16(A0, B1[nt], acc[0][nt], 0, 0, 0);
                acc[1][nt] = __builtin_amdgcn_mfma_f32_16x16x32_bf16(A1, B1[nt], acc[1][nt], 0, 0, 0);
                acc[2][nt] = __builtin_amdgcn_mfma_f32_16x16x32_bf16(A2, B1[nt], acc[2][nt], 0, 0, 0);
            }
        }
        int sb = (s + 3 < KSTEPS) ? s + 3 : KSTEPS - 1;
        LOADB(B1, sb);
    }
    #undef LOADB

    // ---- Phase 3: epilogue — rem features + b1, ReLU, fold w2, reduce over cn ----
    float ps[3][4][2];
    #pragma unroll
    for (int m = 0; m < 3; ++m)
        #pragma unroll
        for (int r = 0; r < 4; ++r) { ps[m][r][0] = 0.f; ps[m][r][1] = 0.f; }

    #pragma unroll
    for (int nt = 0; nt < 2; ++nt) {
        int j = (wid << 5) + (nt << 4) + cn;
        float w1a = w1[(size_t)1536 * HID + j];
        float w1b = w1[(size_t)1537 * HID + j];
        float bb  = b1[j];
        float w20 = w2[(size_t)j * 2 + 0];
        float w21 = w2[(size_t)j * 2 + 1];
        #pragma unroll
        for (int m = 0; m < 3; ++m) {
            #pragma unroll
            for (int r = 0; r < 4; ++r) {
                int pr = (m << 4) + (g << 2) + r;   // C/D: row = (lane>>4)*4 + reg
                float h = acc[m][nt][r] + bb + srem[pr][0] * w1a + srem[pr][1] * w1b;
                h = fmaxf(h, 0.f);
                ps[m][r][0] = fmaf(h, w20, ps[m][r][0]);
                ps[m][r][1] = fmaf(h, w21, ps[m][r][1]);
            }
        }
    }
    #pragma unroll
    for (int m = 0; m < 3; ++m)
        #pragma unroll
        for (int r = 0; r < 4; ++r)
            #pragma unroll
            for (int cc = 0; cc < 2; ++cc)
                #pragma unroll
                for (int off = 1; off < 16; off <<= 1)
                    ps[m][r][cc] += __shfl_xor(ps[m][r][cc], off, 64);
    if (cn == 0) {
        #pragma unroll
        for (int m = 0; m < 3; ++m)
            #pragma unroll
            for (int r = 0; r < 4; ++r) {
                int pr = (m << 4) + (g << 2) + r;
                red[wid][pr][0] = ps[m][r][0];
                red[wid][pr][1] = ps[m][r][1];
            }
    }
    __syncthreads();
    if (t < MT * 2) {
        int pr = t >> 1, c = t & 1;
        float v = b2[c];
        #pragma unroll
        for (int w = 0; w < 16; ++w) v += red[w][pr][c];
        sflow[pr][c] = srem[pr][c] + v;   // remainder_flow
    }
    __syncthreads();

    // ---- Phase 4: bilinear warp loss, 16 lanes per patch (xj = lt) ----
    {
        const int gi = t >> 4, lt = t & 15;
        if (gi < MT) {
            const int pi = gi;
            const float rfy = sflow[pi][0], rfx = sflow[pi][1];
            const int pbase = (pi >> 4) * 24576 + ((pi & 15) << 3);
            float lsum = 0.f;

            const int xj = lt;
            float x  = (float)xj + rfx;
            int   x0 = min(max((int)floorf(x), 0), PSZ - 1);
            int   x1 = min(x0 + 1, PSZ - 1);
            float wx = fminf(fmaxf(x - (float)x0, 0.f), 1.f);
            int   c0 = x0 * 3, c1 = x1 * 3;
            #pragma unroll 4
            for (int yi = 0; yi < PSZ; ++yi) {
                float y  = (float)yi + rfy;
                int   y0 = min(max((int)floorf(y), 0), PSZ - 1);
                int   y1 = min(y0 + 1, PSZ - 1);
                float wy = fminf(fmaxf(y - (float)y0, 0.f), 1.f);
                int r0 = 768 + y0 * 48, r1 = 768 + y1 * 48;
                int ep = yi * 48 + xj * 3;
                #pragma unroll
                for (int cc = 0; cc < 3; ++cc) {
                    int k00 = r0 + c0 + cc, k01 = r0 + c1 + cc;
                    int k10 = r1 + c0 + cc, k11 = r1 + c1 + cc;
                    float v00 = bf2f(feat[pbase + ((k00 >> 3) << 7) + (k00 & 7)]);
                    float v01 = bf2f(feat[pbase + ((k01 >> 3) << 7) + (k01 & 7)]);
                    float v10 = bf2f(feat[pbase + ((k10 >> 3) << 7) + (k10 & 7)]);
                    float v11 = bf2f(feat[pbase + ((k11 >> 3) << 7) + (k11 & 7)]);
                    float a = v00 + wx * (v01 - v00);
                    float b = v10 + wx * (v11 - v10);
                    float warped = a + wy * (b - a);
                    int kp = ep + cc;
                    float d = warped - bf2f(feat[pbase + ((kp >> 3) << 7) + (kp & 7)]);
                    lsum = fmaf(d, d, lsum);
                }
            }
            #pragma unroll
            for (int off = 1; off < 16; off <<= 1)
                lsum += __shfl_xor(lsum, off, 64);

            if (lt == 0) {
                int n = n0 + pi;
                out[(size_t)n * 3 + 0] = (float)sip[pi][0] + rfy;
                out[(size_t)n * 3 + 1] = (float)sip[pi][1] + rfx;
                out[(size_t)n * 3 + 2] = lsum * (1.f / 768.f);
            }
        }
    }
}

extern "C" void kernel_launch(void* const* d_in, const int* in_sizes, int n_in,
                              void* d_out, int out_size, void* d_ws, size_t ws_size,
                              hipStream_t stream) {
    const float* img1  = (const float*)d_in[0];
    const float* img2  = (const float*)d_in[1];
    const float* prior = (const float*)d_in[2];
    const float* w1    = (const float*)d_in[3];
    const float* b1    = (const float*)d_in[4];
    const float* w2    = (const float*)d_in[5];
    const float* b2    = (const float*)d_in[6];
    float* out = (float*)d_out;
    ushort* w1p = (ushort*)d_ws;            // 1536*512*2 B = 1.57 MB

    pack_w1_kernel<<<dim3((1536 * HID) / 256), dim3(256), 0, stream>>>(w1, w1p);

    dim3 grid(NPATCH / MT);                 // 1323 blocks, exact
    dim3 block(NTH);
    lfe_mfma_kernel<<<grid, block, 0, stream>>>(img1, img2, prior, w1, b1, w2, b2, w1p, out);
}